// Round 1
// baseline (889.473 us; speedup 1.0000x reference)
//
#include <hip/hip_runtime.h>
#include <math.h>

// GCN 2-layer: out = sigmoid(Anorm @ relu(Anorm @ x @ W1 + b1) @ W2 + b2)
// Restructured: aggregate raw 3-dim x (linearity), factor norm into
// per-node pre-scale (dinv[src]) and post-scale (dinv[dst]).

static __device__ __forceinline__ long long load_idx(const void* edges, long long pos, int is64) {
    if (is64) return ((const long long*)edges)[pos];
    return (long long)((const int*)edges)[pos];
}

// Detect whether edge_index is int64 or int32: int64 non-negative values
// < 2^31 have all-zero high words at odd int32 positions.
__global__ void k_detect(const int* e32, int* flag) {
    if (blockIdx.x == 0 && threadIdx.x == 0) {
        int is64 = 1;
        for (int k = 0; k < 16; ++k) {
            if (e32[2 * k + 1] != 0) { is64 = 0; break; }
        }
        *flag = is64;
    }
}

__global__ void k_init_deg(float* deg, int n) {
    int i = blockIdx.x * blockDim.x + threadIdx.x;
    if (i < n) deg[i] = 1.0f;  // self-loop contributes 1 to degree
}

__global__ void k_deg(const void* edges, const int* flag, float* deg, long long E) {
    int is64 = *flag;
    long long e = (long long)blockIdx.x * blockDim.x + threadIdx.x;
    if (e < E) {
        long long d = load_idx(edges, E + e, is64);
        atomicAdd(&deg[d], 1.0f);
    }
}

__global__ void k_dinv_xs(const float* __restrict__ x, const float* __restrict__ deg,
                          float* __restrict__ dinv, float4* __restrict__ xs,
                          float4* __restrict__ agg3, int n) {
    int i = blockIdx.x * blockDim.x + threadIdx.x;
    if (i < n) {
        float di = rsqrtf(deg[i]);  // deg >= 1 always (self-loop)
        dinv[i] = di;
        float a = x[3 * i], b = x[3 * i + 1], c = x[3 * i + 2];
        float4 v = make_float4(a * di, b * di, c * di, 0.0f);
        xs[i] = v;
        agg3[i] = v;  // self-loop: xs[i]*1 lands in agg3[i] (scaled by dinv[i] later)
    }
}

__global__ void k_edge1(const void* edges, const int* flag,
                        const float4* __restrict__ xs, float* __restrict__ agg3,
                        long long E) {
    int is64 = *flag;
    long long e = (long long)blockIdx.x * blockDim.x + threadIdx.x;
    if (e < E) {
        long long s = load_idx(edges, e, is64);
        long long d = load_idx(edges, E + e, is64);
        float4 v = xs[s];
        atomicAdd(&agg3[4 * d + 0], v.x);
        atomicAdd(&agg3[4 * d + 1], v.y);
        atomicAdd(&agg3[4 * d + 2], v.z);
    }
}

__global__ void k_node1(const float* __restrict__ dinv, const float4* __restrict__ agg3,
                        const float* __restrict__ W1, const float* __restrict__ b1,
                        const float* __restrict__ W2,
                        float* __restrict__ gs, float* __restrict__ agg1, int n) {
    int i = blockIdx.x * blockDim.x + threadIdx.x;
    if (i < n) {
        float di = dinv[i];
        float4 a = agg3[i];
        float a0 = a.x * di, a1 = a.y * di, a2 = a.z * di;
        float g = 0.0f;
#pragma unroll
        for (int c = 0; c < 16; ++c) {
            // W1 is [3,16] row-major
            float h = fmaf(a0, W1[c], fmaf(a1, W1[16 + c], fmaf(a2, W1[32 + c], b1[c])));
            h = fmaxf(h, 0.0f);  // relu
            g = fmaf(h, W2[c], g);
        }
        float v = g * di;  // pre-scale by dinv[src] for layer-2 aggregation
        gs[i] = v;
        agg1[i] = v;  // self-loop contribution
    }
}

__global__ void k_edge2(const void* edges, const int* flag,
                        const float* __restrict__ gs, float* __restrict__ agg1,
                        long long E) {
    int is64 = *flag;
    long long e = (long long)blockIdx.x * blockDim.x + threadIdx.x;
    if (e < E) {
        long long s = load_idx(edges, e, is64);
        long long d = load_idx(edges, E + e, is64);
        atomicAdd(&agg1[d], gs[s]);
    }
}

__global__ void k_final(const float* __restrict__ dinv, const float* __restrict__ agg1,
                        const float* __restrict__ b2, float* __restrict__ out, int n) {
    int i = blockIdx.x * blockDim.x + threadIdx.x;
    if (i < n) {
        float z = dinv[i] * agg1[i] + b2[0];
        out[i] = 1.0f / (1.0f + expf(-z));
    }
}

extern "C" void kernel_launch(void* const* d_in, const int* in_sizes, int n_in,
                              void* d_out, int out_size, void* d_ws, size_t ws_size,
                              hipStream_t stream) {
    const float* x  = (const float*)d_in[0];
    const void*  ei = d_in[1];
    const float* W1 = (const float*)d_in[2];
    const float* b1 = (const float*)d_in[3];
    const float* W2 = (const float*)d_in[4];
    const float* b2 = (const float*)d_in[5];
    float* out = (float*)d_out;

    const long long n = in_sizes[0] / 3;   // 100000
    const long long E = in_sizes[1] / 2;   // 3200000

    // Workspace carve-up (all byte offsets multiples of 16: n*4 = 400000 = 16*25000)
    char* p = (char*)d_ws;
    float*  deg  = (float*)p;  p += n * sizeof(float);
    float*  dinv = (float*)p;  p += n * sizeof(float);
    float4* xs   = (float4*)p; p += n * sizeof(float4);
    float4* agg3 = (float4*)p; p += n * sizeof(float4);
    float*  gs   = (float*)p;  p += n * sizeof(float);
    float*  agg1 = (float*)p;  p += n * sizeof(float);
    int*    flag = (int*)p;

    const int T = 256;
    const int gN = (int)((n + T - 1) / T);
    const int gE = (int)((E + T - 1) / T);

    k_detect<<<1, 64, 0, stream>>>((const int*)ei, flag);
    k_init_deg<<<gN, T, 0, stream>>>(deg, (int)n);
    k_deg<<<gE, T, 0, stream>>>(ei, flag, deg, E);
    k_dinv_xs<<<gN, T, 0, stream>>>(x, deg, dinv, xs, agg3, (int)n);
    k_edge1<<<gE, T, 0, stream>>>(ei, flag, xs, (float*)agg3, E);
    k_node1<<<gN, T, 0, stream>>>(dinv, agg3, W1, b1, W2, gs, agg1, (int)n);
    k_edge2<<<gE, T, 0, stream>>>(ei, flag, gs, agg1, E);
    k_final<<<gN, T, 0, stream>>>(dinv, agg1, b2, out, (int)n);
}

// Round 2
// 393.051 us; speedup vs baseline: 2.2630x; 2.2630x over previous
//
#include <hip/hip_runtime.h>
#include <math.h>

// GCN 2-layer. R2: scatter-atomics -> padded-CSR build (1 atomic/edge) + atomic-free gathers.
// out = sigmoid(dinv * (selfsum of gs) + b2), gs = dinv * (W2 . relu(W1^T a + b1)), a = dinv * (selfsum of xs), xs = dinv*x.

#define PAD 96   // slots per node; deg ~ Poisson(32), P(deg>96) ~ 1e-18

static __device__ __forceinline__ long long load_idx(const void* edges, long long pos, int is64) {
    if (is64) return ((const long long*)edges)[pos];
    return (long long)((const int*)edges)[pos];
}

__global__ void k_detect(const int* e32, int* flag) {
    if (blockIdx.x == 0 && threadIdx.x == 0) {
        int is64 = 1;
        for (int k = 0; k < 16; ++k) {
            if (e32[2 * k + 1] != 0) { is64 = 0; break; }
        }
        *flag = is64;
    }
}

__global__ void k_zero(int* cnt, int n) {
    int i = blockIdx.x * blockDim.x + threadIdx.x;
    if (i < n) cnt[i] = 0;
}

// One atomic per edge: cursor gives slot AND final degree.
__global__ void k_fill(const void* edges, const int* __restrict__ flag,
                       int* __restrict__ cnt, int* __restrict__ col, long long E) {
    int is64 = *flag;
    long long e = (long long)blockIdx.x * blockDim.x + threadIdx.x;
    if (e < E) {
        int s = (int)load_idx(edges, e, is64);
        int d = (int)load_idx(edges, E + e, is64);
        int slot = atomicAdd(&cnt[d], 1);
        if (slot < PAD) col[(long long)d * PAD + slot] = s;
    }
}

__global__ void k_nodeA(const float* __restrict__ x, const int* __restrict__ cnt,
                        float* __restrict__ dinv, float4* __restrict__ xs, int n) {
    int i = blockIdx.x * blockDim.x + threadIdx.x;
    if (i < n) {
        float di = rsqrtf((float)cnt[i] + 1.0f);  // +1 self-loop
        dinv[i] = di;
        xs[i] = make_float4(x[3 * i] * di, x[3 * i + 1] * di, x[3 * i + 2] * di, 0.0f);
    }
}

// Gather layer-1 aggregation + dense 3->16->relu->1 fused.
__global__ void k_gather1(const int* __restrict__ cnt, const int* __restrict__ col,
                          const float* __restrict__ dinv, const float4* __restrict__ xs,
                          const float* __restrict__ W1, const float* __restrict__ b1,
                          const float* __restrict__ W2, float* __restrict__ gs, int n) {
    int i = blockIdx.x * blockDim.x + threadIdx.x;
    if (i >= n) return;
    float di = dinv[i];
    float4 self = xs[i];  // self-loop term: xs[i]*1
    float a0 = self.x, a1 = self.y, a2 = self.z;
    int deg = min(cnt[i], PAD);
    const int* c = col + (long long)i * PAD;
    int j = 0;
    for (; j + 4 <= deg; j += 4) {
        int s0 = c[j], s1 = c[j + 1], s2 = c[j + 2], s3 = c[j + 3];
        float4 v0 = xs[s0], v1 = xs[s1], v2 = xs[s2], v3 = xs[s3];
        a0 += (v0.x + v1.x) + (v2.x + v3.x);
        a1 += (v0.y + v1.y) + (v2.y + v3.y);
        a2 += (v0.z + v1.z) + (v2.z + v3.z);
    }
    for (; j < deg; ++j) {
        int s = c[j];
        float4 v = xs[s];
        a0 += v.x; a1 += v.y; a2 += v.z;
    }
    a0 *= di; a1 *= di; a2 *= di;
    float g = 0.0f;
#pragma unroll
    for (int k = 0; k < 16; ++k) {  // W1 is [3,16] row-major
        float h = fmaf(a0, W1[k], fmaf(a1, W1[16 + k], fmaf(a2, W1[32 + k], b1[k])));
        h = fmaxf(h, 0.0f);
        g = fmaf(h, W2[k], g);
    }
    gs[i] = g * di;  // pre-scaled by dinv for layer-2 src side
}

// Gather layer-2 (scalar) + sigmoid.
__global__ void k_gather2(const int* __restrict__ cnt, const int* __restrict__ col,
                          const float* __restrict__ dinv, const float* __restrict__ gs,
                          const float* __restrict__ b2, float* __restrict__ out, int n) {
    int i = blockIdx.x * blockDim.x + threadIdx.x;
    if (i >= n) return;
    float acc = gs[i];  // self-loop
    int deg = min(cnt[i], PAD);
    const int* c = col + (long long)i * PAD;
    int j = 0;
    for (; j + 4 <= deg; j += 4) {
        float v0 = gs[c[j]], v1 = gs[c[j + 1]], v2 = gs[c[j + 2]], v3 = gs[c[j + 3]];
        acc += (v0 + v1) + (v2 + v3);
    }
    for (; j < deg; ++j) acc += gs[c[j]];
    float z = dinv[i] * acc + b2[0];
    out[i] = 1.0f / (1.0f + expf(-z));
}

// ---------------- fallback (R1 proven pipeline) ----------------
__global__ void f_init_deg(float* deg, int n) {
    int i = blockIdx.x * blockDim.x + threadIdx.x;
    if (i < n) deg[i] = 1.0f;
}
__global__ void f_deg(const void* edges, const int* flag, float* deg, long long E) {
    int is64 = *flag;
    long long e = (long long)blockIdx.x * blockDim.x + threadIdx.x;
    if (e < E) atomicAdd(&deg[load_idx(edges, E + e, is64)], 1.0f);
}
__global__ void f_dinv_xs(const float* x, const float* deg, float* dinv, float4* xs,
                          float4* agg3, int n) {
    int i = blockIdx.x * blockDim.x + threadIdx.x;
    if (i < n) {
        float di = rsqrtf(deg[i]);
        dinv[i] = di;
        float4 v = make_float4(x[3 * i] * di, x[3 * i + 1] * di, x[3 * i + 2] * di, 0.0f);
        xs[i] = v; agg3[i] = v;
    }
}
__global__ void f_edge1(const void* edges, const int* flag, const float4* xs,
                        float* agg3, long long E) {
    int is64 = *flag;
    long long e = (long long)blockIdx.x * blockDim.x + threadIdx.x;
    if (e < E) {
        long long s = load_idx(edges, e, is64);
        long long d = load_idx(edges, E + e, is64);
        float4 v = xs[s];
        atomicAdd(&agg3[4 * d + 0], v.x);
        atomicAdd(&agg3[4 * d + 1], v.y);
        atomicAdd(&agg3[4 * d + 2], v.z);
    }
}
__global__ void f_node1(const float* dinv, const float4* agg3, const float* W1,
                        const float* b1, const float* W2, float* gs, float* agg1, int n) {
    int i = blockIdx.x * blockDim.x + threadIdx.x;
    if (i < n) {
        float di = dinv[i];
        float4 a = agg3[i];
        float a0 = a.x * di, a1 = a.y * di, a2 = a.z * di;
        float g = 0.0f;
#pragma unroll
        for (int k = 0; k < 16; ++k) {
            float h = fmaf(a0, W1[k], fmaf(a1, W1[16 + k], fmaf(a2, W1[32 + k], b1[k])));
            h = fmaxf(h, 0.0f);
            g = fmaf(h, W2[k], g);
        }
        float v = g * di;
        gs[i] = v; agg1[i] = v;
    }
}
__global__ void f_edge2(const void* edges, const int* flag, const float* gs,
                        float* agg1, long long E) {
    int is64 = *flag;
    long long e = (long long)blockIdx.x * blockDim.x + threadIdx.x;
    if (e < E) atomicAdd(&agg1[load_idx(edges, E + e, is64)], gs[load_idx(edges, e, is64)]);
}
__global__ void f_final(const float* dinv, const float* agg1, const float* b2,
                        float* out, int n) {
    int i = blockIdx.x * blockDim.x + threadIdx.x;
    if (i < n) {
        float z = dinv[i] * agg1[i] + b2[0];
        out[i] = 1.0f / (1.0f + expf(-z));
    }
}

extern "C" void kernel_launch(void* const* d_in, const int* in_sizes, int n_in,
                              void* d_out, int out_size, void* d_ws, size_t ws_size,
                              hipStream_t stream) {
    const float* x  = (const float*)d_in[0];
    const void*  ei = d_in[1];
    const float* W1 = (const float*)d_in[2];
    const float* b1 = (const float*)d_in[3];
    const float* W2 = (const float*)d_in[4];
    const float* b2 = (const float*)d_in[5];
    float* out = (float*)d_out;

    const long long n = in_sizes[0] / 3;
    const long long E = in_sizes[1] / 2;

    const int T = 256;
    const int gN = (int)((n + T - 1) / T);
    const int gE = (int)((E + T - 1) / T);

    // Fast path workspace: xs, col(PAD), cnt, dinv, gs, flag
    size_t need = n * sizeof(float4) + (size_t)n * PAD * sizeof(int)
                + 3 * n * sizeof(float) + 64;

    if (ws_size >= need) {
        char* p = (char*)d_ws;
        float4* xs  = (float4*)p; p += n * sizeof(float4);
        int*   col  = (int*)p;    p += (size_t)n * PAD * sizeof(int);
        int*   cnt  = (int*)p;    p += n * sizeof(int);
        float* dinv = (float*)p;  p += n * sizeof(float);
        float* gs   = (float*)p;  p += n * sizeof(float);
        int*   flag = (int*)p;

        k_detect<<<1, 64, 0, stream>>>((const int*)ei, flag);
        k_zero<<<gN, T, 0, stream>>>(cnt, (int)n);
        k_fill<<<gE, T, 0, stream>>>(ei, flag, cnt, col, E);
        k_nodeA<<<gN, T, 0, stream>>>(x, cnt, dinv, xs, (int)n);
        k_gather1<<<gN, T, 0, stream>>>(cnt, col, dinv, xs, W1, b1, W2, gs, (int)n);
        k_gather2<<<gN, T, 0, stream>>>(cnt, col, dinv, gs, b2, out, (int)n);
    } else {
        // R1 proven atomic pipeline
        char* p = (char*)d_ws;
        float*  deg  = (float*)p;  p += n * sizeof(float);
        float*  dinv = (float*)p;  p += n * sizeof(float);
        float4* xs   = (float4*)p; p += n * sizeof(float4);
        float4* agg3 = (float4*)p; p += n * sizeof(float4);
        float*  gs   = (float*)p;  p += n * sizeof(float);
        float*  agg1 = (float*)p;  p += n * sizeof(float);
        int*    flag = (int*)p;

        k_detect<<<1, 64, 0, stream>>>((const int*)ei, flag);
        f_init_deg<<<gN, T, 0, stream>>>(deg, (int)n);
        f_deg<<<gE, T, 0, stream>>>(ei, flag, deg, E);
        f_dinv_xs<<<gN, T, 0, stream>>>(x, deg, dinv, xs, agg3, (int)n);
        f_edge1<<<gE, T, 0, stream>>>(ei, flag, xs, (float*)agg3, E);
        f_node1<<<gN, T, 0, stream>>>(dinv, agg3, W1, b1, W2, gs, agg1, (int)n);
        f_edge2<<<gE, T, 0, stream>>>(ei, flag, gs, agg1, E);
        f_final<<<gN, T, 0, stream>>>(dinv, agg1, b2, out, (int)n);
    }
}

// Round 3
// 216.580 us; speedup vs baseline: 4.1069x; 1.8148x over previous
//
#include <hip/hip_runtime.h>
#include <math.h>

// GCN 2-layer. R3: bucketed binning — LDS histograms + ~100k global reservation
// atomics replace 3.2M per-edge global atomics-with-return. All per-edge
// aggregation happens in LDS (one block per 256-node bucket).

#define NPB 256        // nodes per bucket (power of 2)
#define SHIFT 8        // log2(NPB)
#define NB_MAX 512     // max buckets supported by LDS arrays in k_bin
#define B1 256         // blocks in k_bin
#define T1 512         // threads per block in k_bin

static __device__ __forceinline__ long long load_idx(const void* edges, long long pos, int is64) {
    if (is64) return ((const long long*)edges)[pos];
    return (long long)((const int*)edges)[pos];
}

__global__ void k_detect(const int* e32, int* flag) {
    if (blockIdx.x == 0 && threadIdx.x == 0) {
        int is64 = 1;
        for (int k = 0; k < 16; ++k) {
            if (e32[2 * k + 1] != 0) { is64 = 0; break; }
        }
        *flag = is64;
    }
}

__global__ void k_zero_cursor(int* cursor, int nb) {
    int i = blockIdx.x * blockDim.x + threadIdx.x;
    if (i < nb) cursor[i] = 0;
}

// Bin edges by destination bucket. Per-edge work is LDS-only; global atomics
// are one reservation per (block, nonempty bucket).
__global__ void k_bin(const void* edges, const int* __restrict__ flag,
                      int* __restrict__ cursor, unsigned int* __restrict__ bin,
                      long long E, int nb, int cap, long long chunk) {
    __shared__ int hist[NB_MAX];
    __shared__ int base[NB_MAX];
    const int tid = threadIdx.x;
    for (int b = tid; b < nb; b += blockDim.x) hist[b] = 0;
    __syncthreads();
    const int is64 = *flag;
    const long long start = (long long)blockIdx.x * chunk;
    const long long end = min(start + chunk, E);
    for (long long e = start + tid; e < end; e += blockDim.x) {
        int d = (int)load_idx(edges, E + e, is64);
        atomicAdd(&hist[d >> SHIFT], 1);               // LDS atomic
    }
    __syncthreads();
    for (int b = tid; b < nb; b += blockDim.x) {
        int h = hist[b];
        base[b] = h ? atomicAdd(&cursor[b], h) : 0;    // global reservation
        hist[b] = 0;                                    // reuse as running offset
    }
    __syncthreads();
    for (long long e = start + tid; e < end; e += blockDim.x) {
        int s = (int)load_idx(edges, e, is64);
        int d = (int)load_idx(edges, E + e, is64);
        int bk = d >> SHIFT;
        int off = base[bk] + atomicAdd(&hist[bk], 1);  // LDS atomic w/ return
        if (off < cap)
            bin[(long long)bk * cap + off] = ((unsigned)(d & (NPB - 1)) << 17) | (unsigned)s;
    }
}

// Per-bucket degree count (LDS) -> dinv, pre-scaled xs.
__global__ void k_deg(const unsigned int* __restrict__ bin, const int* __restrict__ cursor,
                      const float* __restrict__ x, float* __restrict__ dinv,
                      float4* __restrict__ xs, int n, int cap) {
    __shared__ int degl[NPB];
    const int tid = threadIdx.x;
    degl[tid] = 0;
    __syncthreads();
    const int bk = blockIdx.x;
    const int cnt = min(cursor[bk], cap);
    const unsigned int* bp = bin + (long long)bk * cap;
    for (int k = tid; k < cnt; k += blockDim.x)
        atomicAdd(&degl[bp[k] >> 17], 1);
    __syncthreads();
    const int i = bk * NPB + tid;
    if (i < n) {
        float di = rsqrtf((float)degl[tid] + 1.0f);    // +1 self-loop
        dinv[i] = di;
        xs[i] = make_float4(x[3 * i] * di, x[3 * i + 1] * di, x[3 * i + 2] * di, 0.0f);
    }
}

// Layer-1: LDS-accumulated gather of xs + fused 3->16->relu->1 MLP.
__global__ void k_agg1(const unsigned int* __restrict__ bin, const int* __restrict__ cursor,
                       const float* __restrict__ dinv, const float4* __restrict__ xs,
                       const float* __restrict__ W1, const float* __restrict__ b1,
                       const float* __restrict__ W2, float* __restrict__ gs, int n, int cap) {
    __shared__ float ax[NPB], ay[NPB], az[NPB];
    const int tid = threadIdx.x;
    ax[tid] = 0.0f; ay[tid] = 0.0f; az[tid] = 0.0f;
    __syncthreads();
    const int bk = blockIdx.x;
    const int cnt = min(cursor[bk], cap);
    const unsigned int* bp = bin + (long long)bk * cap;
    for (int k = tid; k < cnt; k += blockDim.x) {
        unsigned p = bp[k];
        int s = (int)(p & 0x1FFFFu);
        int dl = (int)(p >> 17);
        float4 v = xs[s];
        atomicAdd(&ax[dl], v.x);
        atomicAdd(&ay[dl], v.y);
        atomicAdd(&az[dl], v.z);
    }
    __syncthreads();
    const int i = bk * NPB + tid;
    if (i < n) {
        float di = dinv[i];
        float4 self = xs[i];
        float a0 = (ax[tid] + self.x) * di;
        float a1 = (ay[tid] + self.y) * di;
        float a2 = (az[tid] + self.z) * di;
        float g = 0.0f;
#pragma unroll
        for (int c = 0; c < 16; ++c) {   // W1 [3,16] row-major
            float h = fmaf(a0, W1[c], fmaf(a1, W1[16 + c], fmaf(a2, W1[32 + c], b1[c])));
            h = fmaxf(h, 0.0f);
            g = fmaf(h, W2[c], g);
        }
        gs[i] = g * di;   // pre-scaled by dinv for layer-2 src side
    }
}

// Layer-2: LDS-accumulated scalar gather + sigmoid.
__global__ void k_agg2(const unsigned int* __restrict__ bin, const int* __restrict__ cursor,
                       const float* __restrict__ dinv, const float* __restrict__ gs,
                       const float* __restrict__ b2, float* __restrict__ out, int n, int cap) {
    __shared__ float acc[NPB];
    const int tid = threadIdx.x;
    acc[tid] = 0.0f;
    __syncthreads();
    const int bk = blockIdx.x;
    const int cnt = min(cursor[bk], cap);
    const unsigned int* bp = bin + (long long)bk * cap;
    for (int k = tid; k < cnt; k += blockDim.x) {
        unsigned p = bp[k];
        atomicAdd(&acc[p >> 17], gs[p & 0x1FFFFu]);
    }
    __syncthreads();
    const int i = bk * NPB + tid;
    if (i < n) {
        float z = dinv[i] * (acc[tid] + gs[i]) + b2[0];
        out[i] = 1.0f / (1.0f + expf(-z));
    }
}

// ---------------- fallback (R1 proven atomic pipeline, small ws) ----------------
__global__ void f_init_deg(float* deg, int n) {
    int i = blockIdx.x * blockDim.x + threadIdx.x;
    if (i < n) deg[i] = 1.0f;
}
__global__ void f_deg(const void* edges, const int* flag, float* deg, long long E) {
    int is64 = *flag;
    long long e = (long long)blockIdx.x * blockDim.x + threadIdx.x;
    if (e < E) atomicAdd(&deg[load_idx(edges, E + e, is64)], 1.0f);
}
__global__ void f_dinv_xs(const float* x, const float* deg, float* dinv, float4* xs,
                          float4* agg3, int n) {
    int i = blockIdx.x * blockDim.x + threadIdx.x;
    if (i < n) {
        float di = rsqrtf(deg[i]);
        dinv[i] = di;
        float4 v = make_float4(x[3 * i] * di, x[3 * i + 1] * di, x[3 * i + 2] * di, 0.0f);
        xs[i] = v; agg3[i] = v;
    }
}
__global__ void f_edge1(const void* edges, const int* flag, const float4* xs,
                        float* agg3, long long E) {
    int is64 = *flag;
    long long e = (long long)blockIdx.x * blockDim.x + threadIdx.x;
    if (e < E) {
        long long s = load_idx(edges, e, is64);
        long long d = load_idx(edges, E + e, is64);
        float4 v = xs[s];
        atomicAdd(&agg3[4 * d + 0], v.x);
        atomicAdd(&agg3[4 * d + 1], v.y);
        atomicAdd(&agg3[4 * d + 2], v.z);
    }
}
__global__ void f_node1(const float* dinv, const float4* agg3, const float* W1,
                        const float* b1, const float* W2, float* gs, float* agg1, int n) {
    int i = blockIdx.x * blockDim.x + threadIdx.x;
    if (i < n) {
        float di = dinv[i];
        float4 a = agg3[i];
        float a0 = a.x * di, a1 = a.y * di, a2 = a.z * di;
        float g = 0.0f;
#pragma unroll
        for (int k = 0; k < 16; ++k) {
            float h = fmaf(a0, W1[k], fmaf(a1, W1[16 + k], fmaf(a2, W1[32 + k], b1[k])));
            h = fmaxf(h, 0.0f);
            g = fmaf(h, W2[k], g);
        }
        float v = g * di;
        gs[i] = v; agg1[i] = v;
    }
}
__global__ void f_edge2(const void* edges, const int* flag, const float* gs,
                        float* agg1, long long E) {
    int is64 = *flag;
    long long e = (long long)blockIdx.x * blockDim.x + threadIdx.x;
    if (e < E) atomicAdd(&agg1[load_idx(edges, E + e, is64)], gs[load_idx(edges, e, is64)]);
}
__global__ void f_final(const float* dinv, const float* agg1, const float* b2,
                        float* out, int n) {
    int i = blockIdx.x * blockDim.x + threadIdx.x;
    if (i < n) {
        float z = dinv[i] * agg1[i] + b2[0];
        out[i] = 1.0f / (1.0f + expf(-z));
    }
}

extern "C" void kernel_launch(void* const* d_in, const int* in_sizes, int n_in,
                              void* d_out, int out_size, void* d_ws, size_t ws_size,
                              hipStream_t stream) {
    const float* x  = (const float*)d_in[0];
    const void*  ei = d_in[1];
    const float* W1 = (const float*)d_in[2];
    const float* b1 = (const float*)d_in[3];
    const float* W2 = (const float*)d_in[4];
    const float* b2 = (const float*)d_in[5];
    float* out = (float*)d_out;

    const long long n = in_sizes[0] / 3;   // 100000
    const long long E = in_sizes[1] / 2;   // 3200000

    const int T = 256;
    const int gN = (int)((n + T - 1) / T);
    const int gE = (int)((E + T - 1) / T);

    const int nb = (int)((n + NPB - 1) / NPB);                       // 391
    long long capll = (E / nb) * 3 / 2 + 256;                        // ~+48 sigma slack
    const int cap = (int)((capll + 63) / 64 * 64);                   // 12544
    size_t need = n * sizeof(float4)                                 // xs
                + (size_t)nb * cap * sizeof(int)                     // bin
                + 2 * n * sizeof(float)                              // dinv, gs
                + nb * sizeof(int) + 128;                            // cursor, flag

    if (nb <= NB_MAX && ws_size >= need) {
        char* p = (char*)d_ws;
        float4* xs   = (float4*)p;       p += n * sizeof(float4);
        unsigned int* bin = (unsigned int*)p; p += (size_t)nb * cap * sizeof(int);
        float* dinv  = (float*)p;        p += n * sizeof(float);
        float* gs    = (float*)p;        p += n * sizeof(float);
        int*   cursor = (int*)p;         p += nb * sizeof(int);
        int*   flag  = (int*)p;

        const long long chunk = (E + B1 - 1) / B1;

        k_detect<<<1, 64, 0, stream>>>((const int*)ei, flag);
        k_zero_cursor<<<(nb + T - 1) / T, T, 0, stream>>>(cursor, nb);
        k_bin<<<B1, T1, 0, stream>>>(ei, flag, cursor, bin, E, nb, cap, chunk);
        k_deg<<<nb, NPB, 0, stream>>>(bin, cursor, x, dinv, xs, (int)n, cap);
        k_agg1<<<nb, NPB, 0, stream>>>(bin, cursor, dinv, xs, W1, b1, W2, gs, (int)n, cap);
        k_agg2<<<nb, NPB, 0, stream>>>(bin, cursor, dinv, gs, b2, out, (int)n, cap);
    } else {
        // R1 proven atomic pipeline
        char* p = (char*)d_ws;
        float*  deg  = (float*)p;  p += n * sizeof(float);
        float*  dinv = (float*)p;  p += n * sizeof(float);
        float4* xs   = (float4*)p; p += n * sizeof(float4);
        float4* agg3 = (float4*)p; p += n * sizeof(float4);
        float*  gs   = (float*)p;  p += n * sizeof(float);
        float*  agg1 = (float*)p;  p += n * sizeof(float);
        int*    flag = (int*)p;

        k_detect<<<1, 64, 0, stream>>>((const int*)ei, flag);
        f_init_deg<<<gN, T, 0, stream>>>(deg, (int)n);
        f_deg<<<gE, T, 0, stream>>>(ei, flag, deg, E);
        f_dinv_xs<<<gN, T, 0, stream>>>(x, deg, dinv, xs, agg3, (int)n);
        f_edge1<<<gE, T, 0, stream>>>(ei, flag, xs, (float*)agg3, E);
        f_node1<<<gN, T, 0, stream>>>(dinv, agg3, W1, b1, W2, gs, agg1, (int)n);
        f_edge2<<<gE, T, 0, stream>>>(ei, flag, gs, agg1, E);
        f_final<<<gN, T, 0, stream>>>(dinv, agg1, b2, out, (int)n);
    }
}

// Round 4
// 202.835 us; speedup vs baseline: 4.3852x; 1.0678x over previous
//
#include <hip/hip_runtime.h>
#include <math.h>

// GCN 2-layer. R4: bucketed binning (R3) + 8-way split partial-sum aggregation
// to fix the 391-block parallelism starvation seen in R3 (Occ 12%, VALU 1.2%).

#define NPB 256        // nodes per bucket (power of 2)
#define SHIFT 8        // log2(NPB)
#define NB_MAX 512     // max buckets supported by LDS arrays in k_bin
#define SPLIT 8        // sub-blocks per bucket in partial kernels
#define B1 384         // blocks in k_bin
#define T1 512         // threads per block in k_bin

static __device__ __forceinline__ long long load_idx(const void* edges, long long pos, int is64) {
    if (is64) return ((const long long*)edges)[pos];
    return (long long)((const int*)edges)[pos];
}

__global__ void k_detect(const int* e32, int* flag) {
    if (blockIdx.x == 0 && threadIdx.x == 0) {
        int is64 = 1;
        for (int k = 0; k < 16; ++k) {
            if (e32[2 * k + 1] != 0) { is64 = 0; break; }
        }
        *flag = is64;
    }
}

__global__ void k_zero_cursor(int* cursor, int nb) {
    int i = blockIdx.x * blockDim.x + threadIdx.x;
    if (i < nb) cursor[i] = 0;
}

// Bin edges by destination bucket. Per-edge work is LDS-only; global atomics
// are one reservation per (block, nonempty bucket).
__global__ void k_bin(const void* edges, const int* __restrict__ flag,
                      int* __restrict__ cursor, unsigned int* __restrict__ bin,
                      long long E, int nb, int cap, long long chunk) {
    __shared__ int hist[NB_MAX];
    __shared__ int base[NB_MAX];
    const int tid = threadIdx.x;
    for (int b = tid; b < nb; b += blockDim.x) hist[b] = 0;
    __syncthreads();
    const int is64 = *flag;
    const long long start = (long long)blockIdx.x * chunk;
    const long long end = min(start + chunk, E);
    for (long long e = start + tid; e < end; e += blockDim.x) {
        int d = (int)load_idx(edges, E + e, is64);
        atomicAdd(&hist[d >> SHIFT], 1);               // LDS atomic
    }
    __syncthreads();
    for (int b = tid; b < nb; b += blockDim.x) {
        int h = hist[b];
        base[b] = h ? atomicAdd(&cursor[b], h) : 0;    // global reservation
        hist[b] = 0;                                    // reuse as running offset
    }
    __syncthreads();
    for (long long e = start + tid; e < end; e += blockDim.x) {
        int s = (int)load_idx(edges, e, is64);
        int d = (int)load_idx(edges, E + e, is64);
        int bk = d >> SHIFT;
        int off = base[bk] + atomicAdd(&hist[bk], 1);  // LDS atomic w/ return
        if (off < cap)
            bin[(long long)bk * cap + off] = ((unsigned)(d & (NPB - 1)) << 17) | (unsigned)s;
    }
}

// ---- degree: 8-way partial count then combine -> dinv, pre-scaled xs ----
__global__ void k_degP(const unsigned int* __restrict__ bin, const int* __restrict__ cursor,
                       int* __restrict__ part, int cap) {
    __shared__ int dcnt[NPB];
    const int tid = threadIdx.x;
    dcnt[tid] = 0;
    __syncthreads();
    const int bk = blockIdx.x >> 3;       // / SPLIT
    const int sub = blockIdx.x & (SPLIT - 1);
    const int cnt = min(cursor[bk], cap);
    const int lo = (int)((long long)cnt * sub / SPLIT);
    const int hi = (int)((long long)cnt * (sub + 1) / SPLIT);
    const unsigned int* bp = bin + (long long)bk * cap;
    for (int k = lo + tid; k < hi; k += NPB)
        atomicAdd(&dcnt[bp[k] >> 17], 1);
    __syncthreads();
    part[(long long)blockIdx.x * NPB + tid] = dcnt[tid];
}

__global__ void k_degC(const int* __restrict__ part, const float* __restrict__ x,
                       float* __restrict__ dinv, float4* __restrict__ xs, int n) {
    const int tid = threadIdx.x;
    const int bk = blockIdx.x;
    const int i = bk * NPB + tid;
    if (i >= n) return;
    int deg = 1;  // self-loop
#pragma unroll
    for (int s = 0; s < SPLIT; ++s)
        deg += part[(long long)(bk * SPLIT + s) * NPB + tid];
    float di = rsqrtf((float)deg);
    dinv[i] = di;
    xs[i] = make_float4(x[3 * i] * di, x[3 * i + 1] * di, x[3 * i + 2] * di, 0.0f);
}

// ---- layer 1: 8-way partial float3 sums, combine + fused 3->16->relu->1 ----
__global__ void k_agg1P(const unsigned int* __restrict__ bin, const int* __restrict__ cursor,
                        const float4* __restrict__ xs, float4* __restrict__ part, int cap) {
    __shared__ float ax[NPB], ay[NPB], az[NPB];
    const int tid = threadIdx.x;
    ax[tid] = 0.0f; ay[tid] = 0.0f; az[tid] = 0.0f;
    __syncthreads();
    const int bk = blockIdx.x >> 3;
    const int sub = blockIdx.x & (SPLIT - 1);
    const int cnt = min(cursor[bk], cap);
    const int lo = (int)((long long)cnt * sub / SPLIT);
    const int hi = (int)((long long)cnt * (sub + 1) / SPLIT);
    const unsigned int* bp = bin + (long long)bk * cap;
    for (int k = lo + tid; k < hi; k += NPB) {
        unsigned p = bp[k];
        float4 v = xs[p & 0x1FFFFu];
        int dl = (int)(p >> 17);
        atomicAdd(&ax[dl], v.x);
        atomicAdd(&ay[dl], v.y);
        atomicAdd(&az[dl], v.z);
    }
    __syncthreads();
    part[(long long)blockIdx.x * NPB + tid] = make_float4(ax[tid], ay[tid], az[tid], 0.0f);
}

__global__ void k_agg1C(const float4* __restrict__ part, const float* __restrict__ dinv,
                        const float4* __restrict__ xs,
                        const float* __restrict__ W1, const float* __restrict__ b1,
                        const float* __restrict__ W2, float* __restrict__ gs, int n) {
    const int tid = threadIdx.x;
    const int bk = blockIdx.x;
    const int i = bk * NPB + tid;
    if (i >= n) return;
    float4 self = xs[i];
    float a0 = self.x, a1 = self.y, a2 = self.z;
#pragma unroll
    for (int s = 0; s < SPLIT; ++s) {
        float4 v = part[(long long)(bk * SPLIT + s) * NPB + tid];
        a0 += v.x; a1 += v.y; a2 += v.z;
    }
    float di = dinv[i];
    a0 *= di; a1 *= di; a2 *= di;
    float g = 0.0f;
#pragma unroll
    for (int c = 0; c < 16; ++c) {   // W1 [3,16] row-major
        float h = fmaf(a0, W1[c], fmaf(a1, W1[16 + c], fmaf(a2, W1[32 + c], b1[c])));
        h = fmaxf(h, 0.0f);
        g = fmaf(h, W2[c], g);
    }
    gs[i] = g * di;   // pre-scaled by dinv for layer-2 src side
}

// ---- layer 2: 8-way partial scalar sums, combine + sigmoid ----
__global__ void k_agg2P(const unsigned int* __restrict__ bin, const int* __restrict__ cursor,
                        const float* __restrict__ gs, float* __restrict__ part, int cap) {
    __shared__ float acc[NPB];
    const int tid = threadIdx.x;
    acc[tid] = 0.0f;
    __syncthreads();
    const int bk = blockIdx.x >> 3;
    const int sub = blockIdx.x & (SPLIT - 1);
    const int cnt = min(cursor[bk], cap);
    const int lo = (int)((long long)cnt * sub / SPLIT);
    const int hi = (int)((long long)cnt * (sub + 1) / SPLIT);
    const unsigned int* bp = bin + (long long)bk * cap;
    for (int k = lo + tid; k < hi; k += NPB) {
        unsigned p = bp[k];
        atomicAdd(&acc[p >> 17], gs[p & 0x1FFFFu]);
    }
    __syncthreads();
    part[(long long)blockIdx.x * NPB + tid] = acc[tid];
}

__global__ void k_agg2C(const float* __restrict__ part, const float* __restrict__ dinv,
                        const float* __restrict__ gs, const float* __restrict__ b2,
                        float* __restrict__ out, int n) {
    const int tid = threadIdx.x;
    const int bk = blockIdx.x;
    const int i = bk * NPB + tid;
    if (i >= n) return;
    float acc = gs[i];  // self-loop
#pragma unroll
    for (int s = 0; s < SPLIT; ++s)
        acc += part[(long long)(bk * SPLIT + s) * NPB + tid];
    float z = dinv[i] * acc + b2[0];
    out[i] = 1.0f / (1.0f + expf(-z));
}

// ---------------- fallback (R1 proven atomic pipeline, small ws) ----------------
__global__ void f_init_deg(float* deg, int n) {
    int i = blockIdx.x * blockDim.x + threadIdx.x;
    if (i < n) deg[i] = 1.0f;
}
__global__ void f_deg(const void* edges, const int* flag, float* deg, long long E) {
    int is64 = *flag;
    long long e = (long long)blockIdx.x * blockDim.x + threadIdx.x;
    if (e < E) atomicAdd(&deg[load_idx(edges, E + e, is64)], 1.0f);
}
__global__ void f_dinv_xs(const float* x, const float* deg, float* dinv, float4* xs,
                          float4* agg3, int n) {
    int i = blockIdx.x * blockDim.x + threadIdx.x;
    if (i < n) {
        float di = rsqrtf(deg[i]);
        dinv[i] = di;
        float4 v = make_float4(x[3 * i] * di, x[3 * i + 1] * di, x[3 * i + 2] * di, 0.0f);
        xs[i] = v; agg3[i] = v;
    }
}
__global__ void f_edge1(const void* edges, const int* flag, const float4* xs,
                        float* agg3, long long E) {
    int is64 = *flag;
    long long e = (long long)blockIdx.x * blockDim.x + threadIdx.x;
    if (e < E) {
        long long s = load_idx(edges, e, is64);
        long long d = load_idx(edges, E + e, is64);
        float4 v = xs[s];
        atomicAdd(&agg3[4 * d + 0], v.x);
        atomicAdd(&agg3[4 * d + 1], v.y);
        atomicAdd(&agg3[4 * d + 2], v.z);
    }
}
__global__ void f_node1(const float* dinv, const float4* agg3, const float* W1,
                        const float* b1, const float* W2, float* gs, float* agg1, int n) {
    int i = blockIdx.x * blockDim.x + threadIdx.x;
    if (i < n) {
        float di = dinv[i];
        float4 a = agg3[i];
        float a0 = a.x * di, a1 = a.y * di, a2 = a.z * di;
        float g = 0.0f;
#pragma unroll
        for (int k = 0; k < 16; ++k) {
            float h = fmaf(a0, W1[k], fmaf(a1, W1[16 + k], fmaf(a2, W1[32 + k], b1[k])));
            h = fmaxf(h, 0.0f);
            g = fmaf(h, W2[k], g);
        }
        float v = g * di;
        gs[i] = v; agg1[i] = v;
    }
}
__global__ void f_edge2(const void* edges, const int* flag, const float* gs,
                        float* agg1, long long E) {
    int is64 = *flag;
    long long e = (long long)blockIdx.x * blockDim.x + threadIdx.x;
    if (e < E) atomicAdd(&agg1[load_idx(edges, E + e, is64)], gs[load_idx(edges, e, is64)]);
}
__global__ void f_final(const float* dinv, const float* agg1, const float* b2,
                        float* out, int n) {
    int i = blockIdx.x * blockDim.x + threadIdx.x;
    if (i < n) {
        float z = dinv[i] * agg1[i] + b2[0];
        out[i] = 1.0f / (1.0f + expf(-z));
    }
}

extern "C" void kernel_launch(void* const* d_in, const int* in_sizes, int n_in,
                              void* d_out, int out_size, void* d_ws, size_t ws_size,
                              hipStream_t stream) {
    const float* x  = (const float*)d_in[0];
    const void*  ei = d_in[1];
    const float* W1 = (const float*)d_in[2];
    const float* b1 = (const float*)d_in[3];
    const float* W2 = (const float*)d_in[4];
    const float* b2 = (const float*)d_in[5];
    float* out = (float*)d_out;

    const long long n = in_sizes[0] / 3;   // 100000
    const long long E = in_sizes[1] / 2;   // 3200000

    const int T = 256;
    const int gN = (int)((n + T - 1) / T);
    const int gE = (int)((E + T - 1) / T);

    const int nb = (int)((n + NPB - 1) / NPB);                       // 391
    long long capll = (E / nb) + (E / nb) / 8 + 256;                 // mean + ~11 sigma
    const int cap = (int)((capll + 63) / 64 * 64);
    size_t need = n * sizeof(float4)                                 // xs
                + (size_t)nb * SPLIT * NPB * sizeof(float4)          // part (aliased)
                + (size_t)nb * cap * sizeof(int)                     // bin
                + 2 * n * sizeof(float)                              // dinv, gs
                + nb * sizeof(int) + 128;                            // cursor, flag

    if (nb <= NB_MAX && n <= (1 << 17) && ws_size >= need) {
        char* p = (char*)d_ws;
        float4* xs   = (float4*)p;       p += n * sizeof(float4);
        float4* part = (float4*)p;       p += (size_t)nb * SPLIT * NPB * sizeof(float4);
        unsigned int* bin = (unsigned int*)p; p += (size_t)nb * cap * sizeof(int);
        float* dinv  = (float*)p;        p += n * sizeof(float);
        float* gs    = (float*)p;        p += n * sizeof(float);
        int*   cursor = (int*)p;         p += nb * sizeof(int);
        int*   flag  = (int*)p;

        const long long chunk = (E + B1 - 1) / B1;

        k_detect<<<1, 64, 0, stream>>>((const int*)ei, flag);
        k_zero_cursor<<<(nb + T - 1) / T, T, 0, stream>>>(cursor, nb);
        k_bin<<<B1, T1, 0, stream>>>(ei, flag, cursor, bin, E, nb, cap, chunk);
        k_degP<<<nb * SPLIT, NPB, 0, stream>>>(bin, cursor, (int*)part, cap);
        k_degC<<<nb, NPB, 0, stream>>>((const int*)part, x, dinv, xs, (int)n);
        k_agg1P<<<nb * SPLIT, NPB, 0, stream>>>(bin, cursor, xs, part, cap);
        k_agg1C<<<nb, NPB, 0, stream>>>(part, dinv, xs, W1, b1, W2, gs, (int)n);
        k_agg2P<<<nb * SPLIT, NPB, 0, stream>>>(bin, cursor, gs, (float*)part, cap);
        k_agg2C<<<nb, NPB, 0, stream>>>((const float*)part, dinv, gs, b2, out, (int)n);
    } else {
        // R1 proven atomic pipeline
        char* p = (char*)d_ws;
        float*  deg  = (float*)p;  p += n * sizeof(float);
        float*  dinv = (float*)p;  p += n * sizeof(float);
        float4* xs   = (float4*)p; p += n * sizeof(float4);
        float4* agg3 = (float4*)p; p += n * sizeof(float4);
        float*  gs   = (float*)p;  p += n * sizeof(float);
        float*  agg1 = (float*)p;  p += n * sizeof(float);
        int*    flag = (int*)p;

        k_detect<<<1, 64, 0, stream>>>((const int*)ei, flag);
        f_init_deg<<<gN, T, 0, stream>>>(deg, (int)n);
        f_deg<<<gE, T, 0, stream>>>(ei, flag, deg, E);
        f_dinv_xs<<<gN, T, 0, stream>>>(x, deg, dinv, xs, agg3, (int)n);
        f_edge1<<<gE, T, 0, stream>>>(ei, flag, xs, (float*)agg3, E);
        f_node1<<<gN, T, 0, stream>>>(dinv, agg3, W1, b1, W2, gs, agg1, (int)n);
        f_edge2<<<gE, T, 0, stream>>>(ei, flag, gs, agg1, E);
        f_final<<<gN, T, 0, stream>>>(dinv, agg1, b2, out, (int)n);
    }
}

// Round 5
// 202.500 us; speedup vs baseline: 4.3925x; 1.0017x over previous
//
#include <hip/hip_runtime.h>
#include <math.h>

// GCN 2-layer. R5: register-staged single-read binning + uint4-vectorized
// partial-aggregation passes (4x memory-level parallelism per wave against
// the uncoalesced-gather line-request wall diagnosed in R4).

#define NPB 256        // nodes per bucket (power of 2)
#define SHIFT 8        // log2(NPB)
#define NB_MAX 512     // max buckets supported by LDS arrays in k_bin
#define SPLIT 8        // sub-blocks per bucket in partial kernels
#define T1 512         // threads per block in k_bin
#define EPT 8          // edges staged per thread in k_bin

static __device__ __forceinline__ long long load_idx(const void* edges, long long pos, int is64) {
    if (is64) return ((const long long*)edges)[pos];
    return (long long)((const int*)edges)[pos];
}

__global__ void k_detect(const int* e32, int* flag) {
    if (blockIdx.x == 0 && threadIdx.x == 0) {
        int is64 = 1;
        for (int k = 0; k < 16; ++k) {
            if (e32[2 * k + 1] != 0) { is64 = 0; break; }
        }
        *flag = is64;
    }
}

__global__ void k_zero_cursor(int* cursor, int nb) {
    int i = blockIdx.x * blockDim.x + threadIdx.x;
    if (i < nb) cursor[i] = 0;
}

// Register-staged binning: ONE pass over the edge list. Each thread stages
// EPT edges in VGPRs, histograms buckets in LDS, block reserves per-bucket
// ranges with global atomics, then fills from registers.
__global__ void k_bin(const void* edges, const int* __restrict__ flag,
                      int* __restrict__ cursor, unsigned int* __restrict__ bin,
                      long long E, int nb, int cap) {
    __shared__ int hist[NB_MAX];
    __shared__ int base[NB_MAX];
    const int tid = threadIdx.x;
    for (int b = tid; b < nb; b += T1) hist[b] = 0;
    __syncthreads();

    const int is64 = *flag;
    const long long start = (long long)blockIdx.x * (T1 * EPT);
    unsigned es[EPT], ed[EPT];

    if (is64) {
        const long long* e64 = (const long long*)edges;
#pragma unroll
        for (int j = 0; j < EPT; ++j) {
            long long e = start + j * T1 + tid;
            if (e < E) {
                es[j] = (unsigned)e64[e];
                ed[j] = (unsigned)e64[E + e];
            } else ed[j] = 0xFFFFFFFFu;
        }
    } else {
        const int* e32 = (const int*)edges;
#pragma unroll
        for (int j = 0; j < EPT; ++j) {
            long long e = start + j * T1 + tid;
            if (e < E) {
                es[j] = (unsigned)e32[e];
                ed[j] = (unsigned)e32[E + e];
            } else ed[j] = 0xFFFFFFFFu;
        }
    }

#pragma unroll
    for (int j = 0; j < EPT; ++j)
        if (ed[j] != 0xFFFFFFFFu) atomicAdd(&hist[ed[j] >> SHIFT], 1);
    __syncthreads();

    for (int b = tid; b < nb; b += T1) {
        int h = hist[b];
        base[b] = h ? atomicAdd(&cursor[b], h) : 0;   // global reservation
        hist[b] = 0;                                   // reuse as running offset
    }
    __syncthreads();

#pragma unroll
    for (int j = 0; j < EPT; ++j) {
        if (ed[j] == 0xFFFFFFFFu) continue;
        int bk = (int)(ed[j] >> SHIFT);
        int off = base[bk] + atomicAdd(&hist[bk], 1);
        if (off < cap)
            bin[(long long)bk * cap + off] = ((ed[j] & (NPB - 1)) << 17) | es[j];
    }
}

// Sub-range [lo,hi) for split `sub`, 4-aligned interior boundaries.
static __device__ __forceinline__ void sub_range(int cnt, int sub, int* lo, int* hi) {
    int l = (int)(((long long)cnt * sub / SPLIT) & ~3LL);
    int h = (sub == SPLIT - 1) ? cnt : (int)(((long long)cnt * (sub + 1) / SPLIT) & ~3LL);
    *lo = l; *hi = h;
}

// ---- degree: vectorized partial count -> combine -> dinv, pre-scaled xs ----
__global__ void k_degP(const unsigned int* __restrict__ bin, const int* __restrict__ cursor,
                       int* __restrict__ part, int cap) {
    __shared__ int dcnt[NPB];
    const int tid = threadIdx.x;
    dcnt[tid] = 0;
    __syncthreads();
    const int bk = blockIdx.x >> 3;
    const int sub = blockIdx.x & (SPLIT - 1);
    const int cnt = min(cursor[bk], cap);
    int lo, hi; sub_range(cnt, sub, &lo, &hi);
    const unsigned int* bp = bin + (long long)bk * cap;
    const int len = hi - lo;
    const int nvec = len >> 2;
    const uint4* bp4 = (const uint4*)(bp + lo);
    for (int v = tid; v < nvec; v += NPB) {
        uint4 q = bp4[v];
        atomicAdd(&dcnt[q.x >> 17], 1);
        atomicAdd(&dcnt[q.y >> 17], 1);
        atomicAdd(&dcnt[q.z >> 17], 1);
        atomicAdd(&dcnt[q.w >> 17], 1);
    }
    for (int k = lo + (nvec << 2) + tid; k < hi; k += NPB)
        atomicAdd(&dcnt[bp[k] >> 17], 1);
    __syncthreads();
    part[(long long)blockIdx.x * NPB + tid] = dcnt[tid];
}

__global__ void k_degC(const int* __restrict__ part, const float* __restrict__ x,
                       float* __restrict__ dinv, float4* __restrict__ xs, int n) {
    const int tid = threadIdx.x;
    const int bk = blockIdx.x;
    const int i = bk * NPB + tid;
    if (i >= n) return;
    int deg = 1;  // self-loop
#pragma unroll
    for (int s = 0; s < SPLIT; ++s)
        deg += part[(long long)(bk * SPLIT + s) * NPB + tid];
    float di = rsqrtf((float)deg);
    dinv[i] = di;
    xs[i] = make_float4(x[3 * i] * di, x[3 * i + 1] * di, x[3 * i + 2] * di, 0.0f);
}

// ---- layer 1: vectorized partial float3 sums ----
__global__ void k_agg1P(const unsigned int* __restrict__ bin, const int* __restrict__ cursor,
                        const float4* __restrict__ xs, float4* __restrict__ part, int cap) {
    __shared__ float ax[NPB], ay[NPB], az[NPB];
    const int tid = threadIdx.x;
    ax[tid] = 0.0f; ay[tid] = 0.0f; az[tid] = 0.0f;
    __syncthreads();
    const int bk = blockIdx.x >> 3;
    const int sub = blockIdx.x & (SPLIT - 1);
    const int cnt = min(cursor[bk], cap);
    int lo, hi; sub_range(cnt, sub, &lo, &hi);
    const unsigned int* bp = bin + (long long)bk * cap;
    const int len = hi - lo;
    const int nvec = len >> 2;
    const uint4* bp4 = (const uint4*)(bp + lo);
    for (int v = tid; v < nvec; v += NPB) {
        uint4 q = bp4[v];
        float4 v0 = xs[q.x & 0x1FFFFu];
        float4 v1 = xs[q.y & 0x1FFFFu];
        float4 v2 = xs[q.z & 0x1FFFFu];
        float4 v3 = xs[q.w & 0x1FFFFu];
        int d0 = q.x >> 17, d1 = q.y >> 17, d2 = q.z >> 17, d3 = q.w >> 17;
        atomicAdd(&ax[d0], v0.x); atomicAdd(&ay[d0], v0.y); atomicAdd(&az[d0], v0.z);
        atomicAdd(&ax[d1], v1.x); atomicAdd(&ay[d1], v1.y); atomicAdd(&az[d1], v1.z);
        atomicAdd(&ax[d2], v2.x); atomicAdd(&ay[d2], v2.y); atomicAdd(&az[d2], v2.z);
        atomicAdd(&ax[d3], v3.x); atomicAdd(&ay[d3], v3.y); atomicAdd(&az[d3], v3.z);
    }
    for (int k = lo + (nvec << 2) + tid; k < hi; k += NPB) {
        unsigned p = bp[k];
        float4 v = xs[p & 0x1FFFFu];
        int dl = (int)(p >> 17);
        atomicAdd(&ax[dl], v.x); atomicAdd(&ay[dl], v.y); atomicAdd(&az[dl], v.z);
    }
    __syncthreads();
    part[(long long)blockIdx.x * NPB + tid] = make_float4(ax[tid], ay[tid], az[tid], 0.0f);
}

__global__ void k_agg1C(const float4* __restrict__ part, const float* __restrict__ dinv,
                        const float4* __restrict__ xs,
                        const float* __restrict__ W1, const float* __restrict__ b1,
                        const float* __restrict__ W2, float* __restrict__ gs, int n) {
    const int tid = threadIdx.x;
    const int bk = blockIdx.x;
    const int i = bk * NPB + tid;
    if (i >= n) return;
    float4 self = xs[i];
    float a0 = self.x, a1 = self.y, a2 = self.z;
#pragma unroll
    for (int s = 0; s < SPLIT; ++s) {
        float4 v = part[(long long)(bk * SPLIT + s) * NPB + tid];
        a0 += v.x; a1 += v.y; a2 += v.z;
    }
    float di = dinv[i];
    a0 *= di; a1 *= di; a2 *= di;
    float g = 0.0f;
#pragma unroll
    for (int c = 0; c < 16; ++c) {   // W1 [3,16] row-major
        float h = fmaf(a0, W1[c], fmaf(a1, W1[16 + c], fmaf(a2, W1[32 + c], b1[c])));
        h = fmaxf(h, 0.0f);
        g = fmaf(h, W2[c], g);
    }
    gs[i] = g * di;   // pre-scaled by dinv for layer-2 src side
}

// ---- layer 2: vectorized partial scalar sums ----
__global__ void k_agg2P(const unsigned int* __restrict__ bin, const int* __restrict__ cursor,
                        const float* __restrict__ gs, float* __restrict__ part, int cap) {
    __shared__ float acc[NPB];
    const int tid = threadIdx.x;
    acc[tid] = 0.0f;
    __syncthreads();
    const int bk = blockIdx.x >> 3;
    const int sub = blockIdx.x & (SPLIT - 1);
    const int cnt = min(cursor[bk], cap);
    int lo, hi; sub_range(cnt, sub, &lo, &hi);
    const unsigned int* bp = bin + (long long)bk * cap;
    const int len = hi - lo;
    const int nvec = len >> 2;
    const uint4* bp4 = (const uint4*)(bp + lo);
    for (int v = tid; v < nvec; v += NPB) {
        uint4 q = bp4[v];
        float g0 = gs[q.x & 0x1FFFFu];
        float g1 = gs[q.y & 0x1FFFFu];
        float g2 = gs[q.z & 0x1FFFFu];
        float g3 = gs[q.w & 0x1FFFFu];
        atomicAdd(&acc[q.x >> 17], g0);
        atomicAdd(&acc[q.y >> 17], g1);
        atomicAdd(&acc[q.z >> 17], g2);
        atomicAdd(&acc[q.w >> 17], g3);
    }
    for (int k = lo + (nvec << 2) + tid; k < hi; k += NPB) {
        unsigned p = bp[k];
        atomicAdd(&acc[p >> 17], gs[p & 0x1FFFFu]);
    }
    __syncthreads();
    part[(long long)blockIdx.x * NPB + tid] = acc[tid];
}

__global__ void k_agg2C(const float* __restrict__ part, const float* __restrict__ dinv,
                        const float* __restrict__ gs, const float* __restrict__ b2,
                        float* __restrict__ out, int n) {
    const int tid = threadIdx.x;
    const int bk = blockIdx.x;
    const int i = bk * NPB + tid;
    if (i >= n) return;
    float acc = gs[i];  // self-loop
#pragma unroll
    for (int s = 0; s < SPLIT; ++s)
        acc += part[(long long)(bk * SPLIT + s) * NPB + tid];
    float z = dinv[i] * acc + b2[0];
    out[i] = 1.0f / (1.0f + expf(-z));
}

// ---------------- fallback (R1 proven atomic pipeline, small ws) ----------------
__global__ void f_init_deg(float* deg, int n) {
    int i = blockIdx.x * blockDim.x + threadIdx.x;
    if (i < n) deg[i] = 1.0f;
}
__global__ void f_deg(const void* edges, const int* flag, float* deg, long long E) {
    int is64 = *flag;
    long long e = (long long)blockIdx.x * blockDim.x + threadIdx.x;
    if (e < E) atomicAdd(&deg[load_idx(edges, E + e, is64)], 1.0f);
}
__global__ void f_dinv_xs(const float* x, const float* deg, float* dinv, float4* xs,
                          float4* agg3, int n) {
    int i = blockIdx.x * blockDim.x + threadIdx.x;
    if (i < n) {
        float di = rsqrtf(deg[i]);
        dinv[i] = di;
        float4 v = make_float4(x[3 * i] * di, x[3 * i + 1] * di, x[3 * i + 2] * di, 0.0f);
        xs[i] = v; agg3[i] = v;
    }
}
__global__ void f_edge1(const void* edges, const int* flag, const float4* xs,
                        float* agg3, long long E) {
    int is64 = *flag;
    long long e = (long long)blockIdx.x * blockDim.x + threadIdx.x;
    if (e < E) {
        long long s = load_idx(edges, e, is64);
        long long d = load_idx(edges, E + e, is64);
        float4 v = xs[s];
        atomicAdd(&agg3[4 * d + 0], v.x);
        atomicAdd(&agg3[4 * d + 1], v.y);
        atomicAdd(&agg3[4 * d + 2], v.z);
    }
}
__global__ void f_node1(const float* dinv, const float4* agg3, const float* W1,
                        const float* b1, const float* W2, float* gs, float* agg1, int n) {
    int i = blockIdx.x * blockDim.x + threadIdx.x;
    if (i < n) {
        float di = dinv[i];
        float4 a = agg3[i];
        float a0 = a.x * di, a1 = a.y * di, a2 = a.z * di;
        float g = 0.0f;
#pragma unroll
        for (int k = 0; k < 16; ++k) {
            float h = fmaf(a0, W1[k], fmaf(a1, W1[16 + k], fmaf(a2, W1[32 + k], b1[k])));
            h = fmaxf(h, 0.0f);
            g = fmaf(h, W2[k], g);
        }
        float v = g * di;
        gs[i] = v; agg1[i] = v;
    }
}
__global__ void f_edge2(const void* edges, const int* flag, const float* gs,
                        float* agg1, long long E) {
    int is64 = *flag;
    long long e = (long long)blockIdx.x * blockDim.x + threadIdx.x;
    if (e < E) atomicAdd(&agg1[load_idx(edges, E + e, is64)], gs[load_idx(edges, e, is64)]);
}
__global__ void f_final(const float* dinv, const float* agg1, const float* b2,
                        float* out, int n) {
    int i = blockIdx.x * blockDim.x + threadIdx.x;
    if (i < n) {
        float z = dinv[i] * agg1[i] + b2[0];
        out[i] = 1.0f / (1.0f + expf(-z));
    }
}

extern "C" void kernel_launch(void* const* d_in, const int* in_sizes, int n_in,
                              void* d_out, int out_size, void* d_ws, size_t ws_size,
                              hipStream_t stream) {
    const float* x  = (const float*)d_in[0];
    const void*  ei = d_in[1];
    const float* W1 = (const float*)d_in[2];
    const float* b1 = (const float*)d_in[3];
    const float* W2 = (const float*)d_in[4];
    const float* b2 = (const float*)d_in[5];
    float* out = (float*)d_out;

    const long long n = in_sizes[0] / 3;   // 100000
    const long long E = in_sizes[1] / 2;   // 3200000

    const int T = 256;
    const int gN = (int)((n + T - 1) / T);
    const int gE = (int)((E + T - 1) / T);

    const int nb = (int)((n + NPB - 1) / NPB);                       // 391
    long long capll = (E / nb) + (E / nb) / 8 + 256;                 // mean + ~11 sigma
    const int cap = (int)((capll + 63) / 64 * 64);
    size_t need = n * sizeof(float4)                                 // xs
                + (size_t)nb * SPLIT * NPB * sizeof(float4)          // part (aliased)
                + (size_t)nb * cap * sizeof(int)                     // bin
                + 2 * n * sizeof(float)                              // dinv, gs
                + nb * sizeof(int) + 128;                            // cursor, flag

    if (nb <= NB_MAX && n <= (1 << 17) && ws_size >= need) {
        char* p = (char*)d_ws;
        float4* xs   = (float4*)p;       p += n * sizeof(float4);
        float4* part = (float4*)p;       p += (size_t)nb * SPLIT * NPB * sizeof(float4);
        unsigned int* bin = (unsigned int*)p; p += (size_t)nb * cap * sizeof(int);
        float* dinv  = (float*)p;        p += n * sizeof(float);
        float* gs    = (float*)p;        p += n * sizeof(float);
        int*   cursor = (int*)p;         p += nb * sizeof(int);
        int*   flag  = (int*)p;

        const long long per_blk = (long long)T1 * EPT;               // 4096 edges/block
        const int gB = (int)((E + per_blk - 1) / per_blk);           // 782

        k_detect<<<1, 64, 0, stream>>>((const int*)ei, flag);
        k_zero_cursor<<<(nb + T - 1) / T, T, 0, stream>>>(cursor, nb);
        k_bin<<<gB, T1, 0, stream>>>(ei, flag, cursor, bin, E, nb, cap);
        k_degP<<<nb * SPLIT, NPB, 0, stream>>>(bin, cursor, (int*)part, cap);
        k_degC<<<nb, NPB, 0, stream>>>((const int*)part, x, dinv, xs, (int)n);
        k_agg1P<<<nb * SPLIT, NPB, 0, stream>>>(bin, cursor, xs, part, cap);
        k_agg1C<<<nb, NPB, 0, stream>>>(part, dinv, xs, W1, b1, W2, gs, (int)n);
        k_agg2P<<<nb * SPLIT, NPB, 0, stream>>>(bin, cursor, gs, (float*)part, cap);
        k_agg2C<<<nb, NPB, 0, stream>>>((const float*)part, dinv, gs, b2, out, (int)n);
    } else {
        // R1 proven atomic pipeline
        char* p = (char*)d_ws;
        float*  deg  = (float*)p;  p += n * sizeof(float);
        float*  dinv = (float*)p;  p += n * sizeof(float);
        float4* xs   = (float4*)p; p += n * sizeof(float4);
        float4* agg3 = (float4*)p; p += n * sizeof(float4);
        float*  gs   = (float*)p;  p += n * sizeof(float);
        float*  agg1 = (float*)p;  p += n * sizeof(float);
        int*    flag = (int*)p;

        k_detect<<<1, 64, 0, stream>>>((const int*)ei, flag);
        f_init_deg<<<gN, T, 0, stream>>>(deg, (int)n);
        f_deg<<<gE, T, 0, stream>>>(ei, flag, deg, E);
        f_dinv_xs<<<gN, T, 0, stream>>>(x, deg, dinv, xs, agg3, (int)n);
        f_edge1<<<gE, T, 0, stream>>>(ei, flag, xs, (float*)agg3, E);
        f_node1<<<gN, T, 0, stream>>>(dinv, agg3, W1, b1, W2, gs, agg1, (int)n);
        f_edge2<<<gE, T, 0, stream>>>(ei, flag, gs, agg1, E);
        f_final<<<gN, T, 0, stream>>>(dinv, agg1, b2, out, (int)n);
    }
}

// Round 6
// 160.384 us; speedup vs baseline: 5.5459x; 1.2626x over previous
//
#include <hip/hip_runtime.h>
#include <math.h>

// GCN 2-layer. R6: agg1P's 3 LDS fp32 atomics/edge -> 1 packed ds_add_u64/edge
// (biased fixed-point, 3x21-bit fields; decode in agg1C using deg from xs.w).
// Model: LDS atomic ~3.7 cyc/lane-op/CU is the wall (R3/R4/R5 invariance).

#define NPB 256        // nodes per bucket (power of 2)
#define SHIFT 8        // log2(NPB)
#define NB_MAX 512     // max buckets supported by LDS arrays in k_bin
#define SPLIT 8        // sub-blocks per bucket in partial kernels
#define T1 512         // threads per block in k_bin
#define EPT 8          // edges staged per thread in k_bin

#define FSCALE 1024.0f     // fixed-point scale (2^10)
#define FBIAS  8192        // per-addend bias (2^13), covers values down to -8
#define FMASK  0x1FFFFFu   // 21-bit field mask

static __device__ __forceinline__ long long load_idx(const void* edges, long long pos, int is64) {
    if (is64) return ((const long long*)edges)[pos];
    return (long long)((const int*)edges)[pos];
}

static __device__ __forceinline__ unsigned long long pack3(float x, float y, float z) {
    unsigned long long e0 = (unsigned)(__float2int_rn(x * FSCALE) + FBIAS);
    unsigned long long e1 = (unsigned)(__float2int_rn(y * FSCALE) + FBIAS);
    unsigned long long e2 = (unsigned)(__float2int_rn(z * FSCALE) + FBIAS);
    return e0 | (e1 << 21) | (e2 << 42);
}

// zero cursors + dtype-detect flag (merged, saves a dispatch)
__global__ void k_zero_cursor(int* cursor, int nb, const int* e32, int* flag) {
    int i = blockIdx.x * blockDim.x + threadIdx.x;
    if (i < nb) cursor[i] = 0;
    if (i == 0) {
        int is64 = 1;
        for (int k = 0; k < 16; ++k) {
            if (e32[2 * k + 1] != 0) { is64 = 0; break; }
        }
        *flag = is64;
    }
}

// Register-staged binning: ONE pass over the edge list.
__global__ void k_bin(const void* edges, const int* __restrict__ flag,
                      int* __restrict__ cursor, unsigned int* __restrict__ bin,
                      long long E, int nb, int cap) {
    __shared__ int hist[NB_MAX];
    __shared__ int base[NB_MAX];
    const int tid = threadIdx.x;
    for (int b = tid; b < nb; b += T1) hist[b] = 0;
    __syncthreads();

    const int is64 = *flag;
    const long long start = (long long)blockIdx.x * (T1 * EPT);
    unsigned es[EPT], ed[EPT];

    if (is64) {
        const long long* e64 = (const long long*)edges;
#pragma unroll
        for (int j = 0; j < EPT; ++j) {
            long long e = start + j * T1 + tid;
            if (e < E) { es[j] = (unsigned)e64[e]; ed[j] = (unsigned)e64[E + e]; }
            else ed[j] = 0xFFFFFFFFu;
        }
    } else {
        const int* e32 = (const int*)edges;
#pragma unroll
        for (int j = 0; j < EPT; ++j) {
            long long e = start + j * T1 + tid;
            if (e < E) { es[j] = (unsigned)e32[e]; ed[j] = (unsigned)e32[E + e]; }
            else ed[j] = 0xFFFFFFFFu;
        }
    }

#pragma unroll
    for (int j = 0; j < EPT; ++j)
        if (ed[j] != 0xFFFFFFFFu) atomicAdd(&hist[ed[j] >> SHIFT], 1);
    __syncthreads();

    for (int b = tid; b < nb; b += T1) {
        int h = hist[b];
        base[b] = h ? atomicAdd(&cursor[b], h) : 0;
        hist[b] = 0;
    }
    __syncthreads();

#pragma unroll
    for (int j = 0; j < EPT; ++j) {
        if (ed[j] == 0xFFFFFFFFu) continue;
        int bk = (int)(ed[j] >> SHIFT);
        int off = base[bk] + atomicAdd(&hist[bk], 1);
        if (off < cap)
            bin[(long long)bk * cap + off] = ((ed[j] & (NPB - 1)) << 17) | es[j];
    }
}

static __device__ __forceinline__ void sub_range(int cnt, int sub, int* lo, int* hi) {
    int l = (int)(((long long)cnt * sub / SPLIT) & ~3LL);
    int h = (sub == SPLIT - 1) ? cnt : (int)(((long long)cnt * (sub + 1) / SPLIT) & ~3LL);
    *lo = l; *hi = h;
}

// ---- degree partial counts ----
__global__ void k_degP(const unsigned int* __restrict__ bin, const int* __restrict__ cursor,
                       int* __restrict__ part, int cap) {
    __shared__ int dcnt[NPB];
    const int tid = threadIdx.x;
    dcnt[tid] = 0;
    __syncthreads();
    const int bk = blockIdx.x >> 3;
    const int sub = blockIdx.x & (SPLIT - 1);
    const int cnt = min(cursor[bk], cap);
    int lo, hi; sub_range(cnt, sub, &lo, &hi);
    const unsigned int* bp = bin + (long long)bk * cap;
    const int len = hi - lo;
    const int nvec = len >> 2;
    const uint4* bp4 = (const uint4*)(bp + lo);
    for (int v = tid; v < nvec; v += NPB) {
        uint4 q = bp4[v];
        atomicAdd(&dcnt[q.x >> 17], 1);
        atomicAdd(&dcnt[q.y >> 17], 1);
        atomicAdd(&dcnt[q.z >> 17], 1);
        atomicAdd(&dcnt[q.w >> 17], 1);
    }
    for (int k = lo + (nvec << 2) + tid; k < hi; k += NPB)
        atomicAdd(&dcnt[bp[k] >> 17], 1);
    __syncthreads();
    part[(long long)blockIdx.x * NPB + tid] = dcnt[tid];
}

// combine -> dinv, pre-scaled xs (xs.w carries edge-degree for agg1C's bias fix)
__global__ void k_degC(const int* __restrict__ part, const float* __restrict__ x,
                       float* __restrict__ dinv, float4* __restrict__ xs, int n) {
    const int tid = threadIdx.x;
    const int bk = blockIdx.x;
    const int i = bk * NPB + tid;
    if (i >= n) return;
    int degE = 0;  // edge-degree (no self-loop)
#pragma unroll
    for (int s = 0; s < SPLIT; ++s)
        degE += part[(long long)(bk * SPLIT + s) * NPB + tid];
    float di = rsqrtf((float)degE + 1.0f);
    dinv[i] = di;
    xs[i] = make_float4(x[3 * i] * di, x[3 * i + 1] * di, x[3 * i + 2] * di, (float)degE);
}

// ---- layer 1: ONE packed u64 LDS atomic per edge ----
__global__ void k_agg1P(const unsigned int* __restrict__ bin, const int* __restrict__ cursor,
                        const float4* __restrict__ xs, unsigned long long* __restrict__ part,
                        int cap) {
    __shared__ unsigned long long acc[NPB];
    const int tid = threadIdx.x;
    acc[tid] = 0ull;
    __syncthreads();
    const int bk = blockIdx.x >> 3;
    const int sub = blockIdx.x & (SPLIT - 1);
    const int cnt = min(cursor[bk], cap);
    int lo, hi; sub_range(cnt, sub, &lo, &hi);
    const unsigned int* bp = bin + (long long)bk * cap;
    const int len = hi - lo;
    const int nvec = len >> 2;
    const uint4* bp4 = (const uint4*)(bp + lo);
    for (int v = tid; v < nvec; v += NPB) {
        uint4 q = bp4[v];
        float4 v0 = xs[q.x & 0x1FFFFu];
        float4 v1 = xs[q.y & 0x1FFFFu];
        float4 v2 = xs[q.z & 0x1FFFFu];
        float4 v3 = xs[q.w & 0x1FFFFu];
        atomicAdd(&acc[q.x >> 17], pack3(v0.x, v0.y, v0.z));
        atomicAdd(&acc[q.y >> 17], pack3(v1.x, v1.y, v1.z));
        atomicAdd(&acc[q.z >> 17], pack3(v2.x, v2.y, v2.z));
        atomicAdd(&acc[q.w >> 17], pack3(v3.x, v3.y, v3.z));
    }
    for (int k = lo + (nvec << 2) + tid; k < hi; k += NPB) {
        unsigned p = bp[k];
        float4 v = xs[p & 0x1FFFFu];
        atomicAdd(&acc[p >> 17], pack3(v.x, v.y, v.z));
    }
    __syncthreads();
    part[(long long)blockIdx.x * NPB + tid] = acc[tid];
}

__global__ void k_agg1C(const unsigned long long* __restrict__ part,
                        const float* __restrict__ dinv, const float4* __restrict__ xs,
                        const float* __restrict__ W1, const float* __restrict__ b1,
                        const float* __restrict__ W2, float* __restrict__ gs, int n) {
    const int tid = threadIdx.x;
    const int bk = blockIdx.x;
    const int i = bk * NPB + tid;
    if (i >= n) return;
    int f0 = 0, f1 = 0, f2 = 0;
#pragma unroll
    for (int s = 0; s < SPLIT; ++s) {
        unsigned long long p = part[(long long)(bk * SPLIT + s) * NPB + tid];
        f0 += (int)(p & FMASK);
        f1 += (int)((p >> 21) & FMASK);
        f2 += (int)((p >> 42) & FMASK);
    }
    float4 self = xs[i];
    int degE = (int)self.w;
    const float inv = 1.0f / FSCALE;
    float a0 = (float)(f0 - FBIAS * degE) * inv + self.x;
    float a1 = (float)(f1 - FBIAS * degE) * inv + self.y;
    float a2 = (float)(f2 - FBIAS * degE) * inv + self.z;
    float di = dinv[i];
    a0 *= di; a1 *= di; a2 *= di;
    float g = 0.0f;
#pragma unroll
    for (int c = 0; c < 16; ++c) {   // W1 [3,16] row-major
        float h = fmaf(a0, W1[c], fmaf(a1, W1[16 + c], fmaf(a2, W1[32 + c], b1[c])));
        h = fmaxf(h, 0.0f);
        g = fmaf(h, W2[c], g);
    }
    gs[i] = g * di;   // pre-scaled by dinv for layer-2 src side
}

// ---- layer 2: scalar partial sums ----
__global__ void k_agg2P(const unsigned int* __restrict__ bin, const int* __restrict__ cursor,
                        const float* __restrict__ gs, float* __restrict__ part, int cap) {
    __shared__ float acc[NPB];
    const int tid = threadIdx.x;
    acc[tid] = 0.0f;
    __syncthreads();
    const int bk = blockIdx.x >> 3;
    const int sub = blockIdx.x & (SPLIT - 1);
    const int cnt = min(cursor[bk], cap);
    int lo, hi; sub_range(cnt, sub, &lo, &hi);
    const unsigned int* bp = bin + (long long)bk * cap;
    const int len = hi - lo;
    const int nvec = len >> 2;
    const uint4* bp4 = (const uint4*)(bp + lo);
    for (int v = tid; v < nvec; v += NPB) {
        uint4 q = bp4[v];
        float g0 = gs[q.x & 0x1FFFFu];
        float g1 = gs[q.y & 0x1FFFFu];
        float g2 = gs[q.z & 0x1FFFFu];
        float g3 = gs[q.w & 0x1FFFFu];
        atomicAdd(&acc[q.x >> 17], g0);
        atomicAdd(&acc[q.y >> 17], g1);
        atomicAdd(&acc[q.z >> 17], g2);
        atomicAdd(&acc[q.w >> 17], g3);
    }
    for (int k = lo + (nvec << 2) + tid; k < hi; k += NPB) {
        unsigned p = bp[k];
        atomicAdd(&acc[p >> 17], gs[p & 0x1FFFFu]);
    }
    __syncthreads();
    part[(long long)blockIdx.x * NPB + tid] = acc[tid];
}

__global__ void k_agg2C(const float* __restrict__ part, const float* __restrict__ dinv,
                        const float* __restrict__ gs, const float* __restrict__ b2,
                        float* __restrict__ out, int n) {
    const int tid = threadIdx.x;
    const int bk = blockIdx.x;
    const int i = bk * NPB + tid;
    if (i >= n) return;
    float acc = gs[i];  // self-loop
#pragma unroll
    for (int s = 0; s < SPLIT; ++s)
        acc += part[(long long)(bk * SPLIT + s) * NPB + tid];
    float z = dinv[i] * acc + b2[0];
    out[i] = 1.0f / (1.0f + expf(-z));
}

// ---------------- fallback (R1 proven atomic pipeline, small ws) ----------------
__global__ void k_detect(const int* e32, int* flag) {
    if (blockIdx.x == 0 && threadIdx.x == 0) {
        int is64 = 1;
        for (int k = 0; k < 16; ++k) {
            if (e32[2 * k + 1] != 0) { is64 = 0; break; }
        }
        *flag = is64;
    }
}
__global__ void f_init_deg(float* deg, int n) {
    int i = blockIdx.x * blockDim.x + threadIdx.x;
    if (i < n) deg[i] = 1.0f;
}
__global__ void f_deg(const void* edges, const int* flag, float* deg, long long E) {
    int is64 = *flag;
    long long e = (long long)blockIdx.x * blockDim.x + threadIdx.x;
    if (e < E) atomicAdd(&deg[load_idx(edges, E + e, is64)], 1.0f);
}
__global__ void f_dinv_xs(const float* x, const float* deg, float* dinv, float4* xs,
                          float4* agg3, int n) {
    int i = blockIdx.x * blockDim.x + threadIdx.x;
    if (i < n) {
        float di = rsqrtf(deg[i]);
        dinv[i] = di;
        float4 v = make_float4(x[3 * i] * di, x[3 * i + 1] * di, x[3 * i + 2] * di, 0.0f);
        xs[i] = v; agg3[i] = v;
    }
}
__global__ void f_edge1(const void* edges, const int* flag, const float4* xs,
                        float* agg3, long long E) {
    int is64 = *flag;
    long long e = (long long)blockIdx.x * blockDim.x + threadIdx.x;
    if (e < E) {
        long long s = load_idx(edges, e, is64);
        long long d = load_idx(edges, E + e, is64);
        float4 v = xs[s];
        atomicAdd(&agg3[4 * d + 0], v.x);
        atomicAdd(&agg3[4 * d + 1], v.y);
        atomicAdd(&agg3[4 * d + 2], v.z);
    }
}
__global__ void f_node1(const float* dinv, const float4* agg3, const float* W1,
                        const float* b1, const float* W2, float* gs, float* agg1, int n) {
    int i = blockIdx.x * blockDim.x + threadIdx.x;
    if (i < n) {
        float di = dinv[i];
        float4 a = agg3[i];
        float a0 = a.x * di, a1 = a.y * di, a2 = a.z * di;
        float g = 0.0f;
#pragma unroll
        for (int k = 0; k < 16; ++k) {
            float h = fmaf(a0, W1[k], fmaf(a1, W1[16 + k], fmaf(a2, W1[32 + k], b1[k])));
            h = fmaxf(h, 0.0f);
            g = fmaf(h, W2[k], g);
        }
        float v = g * di;
        gs[i] = v; agg1[i] = v;
    }
}
__global__ void f_edge2(const void* edges, const int* flag, const float* gs,
                        float* agg1, long long E) {
    int is64 = *flag;
    long long e = (long long)blockIdx.x * blockDim.x + threadIdx.x;
    if (e < E) atomicAdd(&agg1[load_idx(edges, E + e, is64)], gs[load_idx(edges, e, is64)]);
}
__global__ void f_final(const float* dinv, const float* agg1, const float* b2,
                        float* out, int n) {
    int i = blockIdx.x * blockDim.x + threadIdx.x;
    if (i < n) {
        float z = dinv[i] * agg1[i] + b2[0];
        out[i] = 1.0f / (1.0f + expf(-z));
    }
}

extern "C" void kernel_launch(void* const* d_in, const int* in_sizes, int n_in,
                              void* d_out, int out_size, void* d_ws, size_t ws_size,
                              hipStream_t stream) {
    const float* x  = (const float*)d_in[0];
    const void*  ei = d_in[1];
    const float* W1 = (const float*)d_in[2];
    const float* b1 = (const float*)d_in[3];
    const float* W2 = (const float*)d_in[4];
    const float* b2 = (const float*)d_in[5];
    float* out = (float*)d_out;

    const long long n = in_sizes[0] / 3;   // 100000
    const long long E = in_sizes[1] / 2;   // 3200000

    const int T = 256;
    const int gN = (int)((n + T - 1) / T);
    const int gE = (int)((E + T - 1) / T);

    const int nb = (int)((n + NPB - 1) / NPB);                       // 391
    long long capll = (E / nb) + (E / nb) / 8 + 256;                 // mean + ~11 sigma
    const int cap = (int)((capll + 63) / 64 * 64);
    size_t need = n * sizeof(float4)                                 // xs
                + (size_t)nb * SPLIT * NPB * sizeof(float4)          // part (aliased)
                + (size_t)nb * cap * sizeof(int)                     // bin
                + 2 * n * sizeof(float)                              // dinv, gs
                + nb * sizeof(int) + 128;                            // cursor, flag

    if (nb <= NB_MAX && n <= (1 << 17) && ws_size >= need) {
        char* p = (char*)d_ws;
        float4* xs   = (float4*)p;       p += n * sizeof(float4);
        char*  partb = p;                p += (size_t)nb * SPLIT * NPB * sizeof(float4);
        unsigned int* bin = (unsigned int*)p; p += (size_t)nb * cap * sizeof(int);
        float* dinv  = (float*)p;        p += n * sizeof(float);
        float* gs    = (float*)p;        p += n * sizeof(float);
        int*   cursor = (int*)p;         p += nb * sizeof(int);
        int*   flag  = (int*)p;

        const long long per_blk = (long long)T1 * EPT;               // 4096 edges/block
        const int gB = (int)((E + per_blk - 1) / per_blk);           // 782

        k_zero_cursor<<<(nb + T - 1) / T, T, 0, stream>>>(cursor, nb, (const int*)ei, flag);
        k_bin<<<gB, T1, 0, stream>>>(ei, flag, cursor, bin, E, nb, cap);
        k_degP<<<nb * SPLIT, NPB, 0, stream>>>(bin, cursor, (int*)partb, cap);
        k_degC<<<nb, NPB, 0, stream>>>((const int*)partb, x, dinv, xs, (int)n);
        k_agg1P<<<nb * SPLIT, NPB, 0, stream>>>(bin, cursor, xs, (unsigned long long*)partb, cap);
        k_agg1C<<<nb, NPB, 0, stream>>>((const unsigned long long*)partb, dinv, xs, W1, b1, W2, gs, (int)n);
        k_agg2P<<<nb * SPLIT, NPB, 0, stream>>>(bin, cursor, gs, (float*)partb, cap);
        k_agg2C<<<nb, NPB, 0, stream>>>((const float*)partb, dinv, gs, b2, out, (int)n);
    } else {
        // R1 proven atomic pipeline
        char* p = (char*)d_ws;
        float*  deg  = (float*)p;  p += n * sizeof(float);
        float*  dinv = (float*)p;  p += n * sizeof(float);
        float4* xs   = (float4*)p; p += n * sizeof(float4);
        float4* agg3 = (float4*)p; p += n * sizeof(float4);
        float*  gs   = (float*)p;  p += n * sizeof(float);
        float*  agg1 = (float*)p;  p += n * sizeof(float);
        int*    flag = (int*)p;

        k_detect<<<1, 64, 0, stream>>>((const int*)ei, flag);
        f_init_deg<<<gN, T, 0, stream>>>(deg, (int)n);
        f_deg<<<gE, T, 0, stream>>>(ei, flag, deg, E);
        f_dinv_xs<<<gN, T, 0, stream>>>(x, deg, dinv, xs, agg3, (int)n);
        f_edge1<<<gE, T, 0, stream>>>(ei, flag, xs, (float*)agg3, E);
        f_node1<<<gN, T, 0, stream>>>(dinv, agg3, W1, b1, W2, gs, agg1, (int)n);
        f_edge2<<<gE, T, 0, stream>>>(ei, flag, gs, agg1, E);
        f_final<<<gN, T, 0, stream>>>(dinv, agg1, b2, out, (int)n);
    }
}